// Round 7
// baseline (480.233 us; speedup 1.0000x reference)
//
#include <hip/hip_runtime.h>
#include <stdint.h>

// ---------------------------------------------------------------------------
// KnowledgeCircuit: B=4 S=2048 D=1024 N=64 R=128, M = B*S = 8192 tokens.
// Round 12 = Round 11 resubmit (bench infra failed twice; no counter data).
// GEMM2 occupancy fix. GEMM2 (M=8192,N=1024,K=8192) at 128x128
// tiles has grid 512 = exactly 2 blocks/CU (grid-limited, Occupancy 21%) --
// the 2-barrier structure's ~20% drain is hidden only by cross-block TLP
// (m97 sweet spot = 3 blocks/CU). Shrink GEMM2 tile to 128x64 (TN template):
// grid (64,16) = 1024 blocks = 4/CU, launch_bounds(256,4), LDS 24 KB.
// B-staging for 64-row tiles reuses the proven fold-kernel pattern.
//   GEMM1: y[m, n*128+r] = sum_d x[m,d] F[n,d,r]   (kc_gemm<...,128>, bf16)
//   mid  : h[m,r] = sum_n w1[m,n] y[m,n*128+r];  y <- g = w2 (x) h  (16B/lane)
//   GEMM2: out = g @ Rk_flat                       (kc_gemm<...,64>, fp32)
// Core GEMM: 2x2 waves, BK=64, global_load_lds, XOR-swizzled LDS (0 confl).
// ---------------------------------------------------------------------------

typedef unsigned short ushort_t;
typedef __attribute__((ext_vector_type(8))) short frag_t;   // 8 bf16
typedef __attribute__((ext_vector_type(4))) float f32x4;

#define BK 64

__device__ __forceinline__ unsigned short f2bf(float f) {
    unsigned int u = __builtin_bit_cast(unsigned int, f);
    u = (u + 0x7FFFu + ((u >> 16) & 1u)) >> 16;   // RTNE
    return (unsigned short)u;
}
__device__ __forceinline__ float bf2f_lo(unsigned int v) {
    return __builtin_bit_cast(float, v << 16);
}
__device__ __forceinline__ float bf2f_hi(unsigned int v) {
    return __builtin_bit_cast(float, v & 0xFFFF0000u);
}

__device__ __forceinline__ void glds16(const ushort_t* g, ushort_t* l) {
    __builtin_amdgcn_global_load_lds(
        (const __attribute__((address_space(1))) unsigned int*)g,
        (__attribute__((address_space(3))) unsigned int*)l,
        16, 0, 0);
}

// ---------------- prepass: fp32 -> bf16 elementwise -------------------------
__global__ __launch_bounds__(256) void convert_bf(const float* __restrict__ in,
                                                  ushort_t* __restrict__ out, int n8) {
    int idx = blockIdx.x * 256 + threadIdx.x;
    if (idx >= n8) return;
    const float4 v0 = ((const float4*)in)[idx * 2];
    const float4 v1 = ((const float4*)in)[idx * 2 + 1];
    unsigned short b[8] = { f2bf(v0.x), f2bf(v0.y), f2bf(v0.z), f2bf(v0.w),
                            f2bf(v1.x), f2bf(v1.y), f2bf(v1.z), f2bf(v1.w) };
    ((uint4*)out)[idx] = *(const uint4*)b;
}

// ---------------- prepass: fp32 RxC -> bf16 CxR transpose (batched) ---------
__global__ __launch_bounds__(256) void transpose_bf(const float* __restrict__ in,
                                                    ushort_t* __restrict__ out,
                                                    int R, int C,
                                                    long in_bstride, long out_bstride) {
    __shared__ float tile[64][65];
    in  += (long)blockIdx.z * in_bstride;
    out += (long)blockIdx.z * out_bstride;
    const int t  = threadIdx.x;
    const int r0 = blockIdx.x * 64;
    const int c0 = blockIdx.y * 64;
    const int ci = t & 63;
    const int rb = t >> 6;
    #pragma unroll
    for (int p = 0; p < 16; ++p)
        tile[rb + 4 * p][ci] = in[(size_t)(r0 + rb + 4 * p) * C + c0 + ci];
    __syncthreads();
    const int cw = t >> 2;
    const int rg = (t & 3) * 16;
    unsigned short buf[16];
    #pragma unroll
    for (int k = 0; k < 16; ++k)
        buf[k] = f2bf(tile[rg + k][cw]);
    uint4* dst = (uint4*)&out[(size_t)(c0 + cw) * R + r0 + rg];
    dst[0] = *(const uint4*)&buf[0];
    dst[1] = *(const uint4*)&buf[8];
}

// ---------------- mid (vectorized): h = w1-reduce(y); y <- g = w2 (x) h -----
// One wave per token row. Lane l: n-class ng = l>>4 (n = 4i+ng, i=0..15),
// rp-quad rp4 = l&15. 16B/lane fully coalesced both directions;
// h partials combined across the 4 n-classes via shfl_xor 16/32.
__global__ __launch_bounds__(256) void mid_fuse_v(ushort_t* __restrict__ y,
                                                  const float* __restrict__ w1,
                                                  const float* __restrict__ w2) {
    const int m    = blockIdx.x * 4 + (threadIdx.x >> 6);
    const int lane = threadIdx.x & 63;
    uint4* yrow = (uint4*)(y + (size_t)m * 8192);   // 1024 uint4 per row
    const float* w1r = w1 + (size_t)m * 64;
    const float* w2r = w2 + (size_t)m * 64;
    const int ng  = lane >> 4;
    const int rp4 = lane & 15;

    float h[8];
    #pragma unroll
    for (int k = 0; k < 8; ++k) h[k] = 0.f;

    #pragma unroll
    for (int i = 0; i < 16; ++i) {
        const int n = i * 4 + ng;
        const uint4 v = yrow[n * 16 + rp4];        // u32 idx n*64 + rp4*4
        const float w = w1r[n];
        h[0] += w * bf2f_lo(v.x); h[1] += w * bf2f_hi(v.x);
        h[2] += w * bf2f_lo(v.y); h[3] += w * bf2f_hi(v.y);
        h[4] += w * bf2f_lo(v.z); h[5] += w * bf2f_hi(v.z);
        h[6] += w * bf2f_lo(v.w); h[7] += w * bf2f_hi(v.w);
    }
    #pragma unroll
    for (int k = 0; k < 8; ++k) {
        h[k] += __shfl_xor(h[k], 16, 64);
        h[k] += __shfl_xor(h[k], 32, 64);
    }
    // g[m, n*128+r] = w2[m,n] * h[m,r], written in place (same coords as read)
    #pragma unroll
    for (int i = 0; i < 16; ++i) {
        const int n = i * 4 + ng;
        const float w = w2r[n];
        uint4 o;
        o.x = (unsigned)f2bf(w * h[0]) | ((unsigned)f2bf(w * h[1]) << 16);
        o.y = (unsigned)f2bf(w * h[2]) | ((unsigned)f2bf(w * h[3]) << 16);
        o.z = (unsigned)f2bf(w * h[4]) | ((unsigned)f2bf(w * h[5]) << 16);
        o.w = (unsigned)f2bf(w * h[6]) | ((unsigned)f2bf(w * h[7]) << 16);
        yrow[n * 16 + rp4] = o;
    }
}

// ---------------- pure GEMM (128 x TN, TN in {128, 64}) ---------------------
// C[m,n] = sum_k Ab[m,k] * Bt[n,k]; 2x2 waves.
// TN=128: 64x64/wave (round-5 known-good, byte-identical schedule).
// TN=64 : 64x32/wave, B-tile 64 rows (fold-kernel staging pattern),
//         LDS 24 KB, 4 blocks/CU at grid >= 1024.
template<bool OUT_BF16, int TN, int MINW>
__global__ __launch_bounds__(256, MINW)
void kc_gemm(const ushort_t* __restrict__ Ab, const ushort_t* __restrict__ Bt,
             void* __restrict__ Cout, int ldA, int ldB, int ldC, int ksteps)
{
    constexpr int NBJ = (TN == 128) ? 4 : 2;   // B frags / j-tiles per wave
    constexpr int BCH = (TN == 128) ? 4 : 2;   // B staging chunks per wave

    __shared__ ushort_t As[128 * BK];   // 16 KB, XOR-swizzled
    __shared__ ushort_t Bs[TN * BK];    // 16 or 8 KB

    const int t    = threadIdx.x;
    const int lane = t & 63;
    const int wv   = t >> 6;
    const int m0   = blockIdx.x * 128;
    const int n0   = blockIdx.y * TN;

    const int wm = (wv & 1) * 64;
    const int wn = (wv >> 1) * (TN / 2);
    const int fr = lane & 15;
    const int q  = lane >> 4;
    const int e  = fr & 7;

    int arow[4], acol[4], brow[BCH], bcol[BCH];
    #pragma unroll
    for (int c = 0; c < 4; ++c) {
        const int s = (wv * 4 + c) * 64 + lane;
        arow[c] = s >> 3;
        acol[c] = ((s & 7) ^ (arow[c] & 7)) * 8;   // XOR swizzle in global k
    }
    #pragma unroll
    for (int c = 0; c < BCH; ++c) {
        const int s = (wv * BCH + c) * 64 + lane;
        brow[c] = s >> 3;
        bcol[c] = ((s & 7) ^ (brow[c] & 7)) * 8;
    }

    f32x4 acc[4][NBJ];
    #pragma unroll
    for (int i = 0; i < 4; ++i)
        #pragma unroll
        for (int j = 0; j < NBJ; ++j)
            acc[i][j] = (f32x4){0.f, 0.f, 0.f, 0.f};

    for (int ss = 0; ss < ksteps; ++ss) {
        const int k0 = ss * BK;

        __syncthreads();
        #pragma unroll
        for (int c = 0; c < 4; ++c)
            glds16(Ab + (size_t)(m0 + arow[c]) * ldA + k0 + acol[c],
                   &As[(wv * 4 + c) * 512]);
        #pragma unroll
        for (int c = 0; c < BCH; ++c)
            glds16(Bt + (size_t)(n0 + brow[c]) * ldB + k0 + bcol[c],
                   &Bs[(wv * BCH + c) * 512]);
        __syncthreads();

        #pragma unroll
        for (int kk = 0; kk < 2; ++kk) {
            const int csw = (kk * 4 + q) ^ e;
            frag_t a[4], b[NBJ];
            #pragma unroll
            for (int i = 0; i < 4; ++i)
                a[i] = *(const frag_t*)&As[((wm + 16 * i + fr) * 8 + csw) * 8];
            #pragma unroll
            for (int j = 0; j < NBJ; ++j)
                b[j] = *(const frag_t*)&Bs[((wn + 16 * j + fr) * 8 + csw) * 8];
            #pragma unroll
            for (int i = 0; i < 4; ++i)
                #pragma unroll
                for (int j = 0; j < NBJ; ++j)
                    acc[i][j] = __builtin_amdgcn_mfma_f32_16x16x32_bf16(
                                    a[i], b[j], acc[i][j], 0, 0, 0);
        }
    }

    // epilogue: C/D layout col=lane&15, row=q*4+reg
    #pragma unroll
    for (int i = 0; i < 4; ++i) {
        #pragma unroll
        for (int r = 0; r < 4; ++r) {
            const int gm = m0 + wm + 16 * i + q * 4 + r;
            #pragma unroll
            for (int j = 0; j < NBJ; ++j) {
                const int gn = n0 + wn + 16 * j + fr;
                if constexpr (OUT_BF16)
                    ((ushort_t*)Cout)[(size_t)gm * ldC + gn] = f2bf(acc[i][j][r]);
                else
                    ((float*)Cout)[(size_t)gm * ldC + gn] = acc[i][j][r];
            }
        }
    }
}

// ---------------- fallback fold-GEMM (round-3, known-good) ------------------
template<int SHIFT, int SEG_STEPS, bool ATOMIC>
__global__ __launch_bounds__(256, 4)
void kc_gemm_fold(const ushort_t* __restrict__ Ab, const float* __restrict__ W,
                  const ushort_t* __restrict__ Bt, float* __restrict__ C,
                  int ldA, int ldB, int ldC, int ksteps)
{
    __shared__ ushort_t As[64 * BK];
    __shared__ ushort_t Bs[128 * BK];
    const int t = threadIdx.x, lane = t & 63, wv = t >> 6;
    const int m0 = blockIdx.x * 64, n0 = blockIdx.y * 128;
    const int kbase = blockIdx.z * ksteps * BK;
    const int wm = (wv & 1) * 32, wn = (wv >> 1) * 64;
    const int fr = lane & 15, q = lane >> 4, e = fr & 7;
    int arow[2], acol[2], brow[4], bcol[4];
    #pragma unroll
    for (int c = 0; c < 2; ++c) {
        const int s = (wv * 2 + c) * 64 + lane;
        arow[c] = s >> 3; acol[c] = ((s & 7) ^ (arow[c] & 7)) * 8;
    }
    #pragma unroll
    for (int c = 0; c < 4; ++c) {
        const int s = (wv * 4 + c) * 64 + lane;
        brow[c] = s >> 3; bcol[c] = ((s & 7) ^ (brow[c] & 7)) * 8;
    }
    f32x4 acc_out[2][4];
    #pragma unroll
    for (int i = 0; i < 2; ++i)
        #pragma unroll
        for (int j = 0; j < 4; ++j) acc_out[i][j] = (f32x4){0.f,0.f,0.f,0.f};
    const int nsegs = ksteps / SEG_STEPS;
    for (int seg = 0; seg < nsegs; ++seg) {
        const int segk = kbase + seg * SEG_STEPS * BK;
        const int nidx = segk >> SHIFT;
        f32x4 acc_in[2][4];
        #pragma unroll
        for (int i = 0; i < 2; ++i)
            #pragma unroll
            for (int j = 0; j < 4; ++j) acc_in[i][j] = (f32x4){0.f,0.f,0.f,0.f};
        for (int ss = 0; ss < SEG_STEPS; ++ss) {
            const int k0 = segk + ss * BK;
            const int d0 = k0 & ((1 << SHIFT) - 1);
            __syncthreads();
            #pragma unroll
            for (int c = 0; c < 2; ++c)
                glds16(Ab + (size_t)(m0 + arow[c]) * ldA + d0 + acol[c],
                       &As[(wv * 2 + c) * 512]);
            #pragma unroll
            for (int c = 0; c < 4; ++c)
                glds16(Bt + (size_t)(n0 + brow[c]) * ldB + k0 + bcol[c],
                       &Bs[(wv * 4 + c) * 512]);
            __syncthreads();
            #pragma unroll
            for (int kk = 0; kk < 2; ++kk) {
                const int csw = (kk * 4 + q) ^ e;
                frag_t a[2], b[4];
                #pragma unroll
                for (int i = 0; i < 2; ++i)
                    a[i] = *(const frag_t*)&As[((wm + 16*i + fr) * 8 + csw) * 8];
                #pragma unroll
                for (int j = 0; j < 4; ++j)
                    b[j] = *(const frag_t*)&Bs[((wn + 16*j + fr) * 8 + csw) * 8];
                #pragma unroll
                for (int i = 0; i < 2; ++i)
                    #pragma unroll
                    for (int j = 0; j < 4; ++j)
                        acc_in[i][j] = __builtin_amdgcn_mfma_f32_16x16x32_bf16(
                                           a[i], b[j], acc_in[i][j], 0, 0, 0);
            }
        }
        #pragma unroll
        for (int i = 0; i < 2; ++i)
            #pragma unroll
            for (int r = 0; r < 4; ++r) {
                const int gm = m0 + wm + 16*i + q*4 + r;
                const float w = W[(size_t)gm * 64 + nidx];
                #pragma unroll
                for (int j = 0; j < 4; ++j) acc_out[i][j][r] += w * acc_in[i][j][r];
            }
    }
    #pragma unroll
    for (int i = 0; i < 2; ++i)
        #pragma unroll
        for (int j = 0; j < 4; ++j)
            #pragma unroll
            for (int r = 0; r < 4; ++r) {
                const int gm = m0 + wm + 16*i + q*4 + r;
                const int gn = n0 + wn + 16*j + fr;
                if constexpr (ATOMIC) atomicAdd(&C[(size_t)gm * ldC + gn], acc_out[i][j][r]);
                else C[(size_t)gm * ldC + gn] = acc_out[i][j][r];
            }
}

extern "C" void kernel_launch(void* const* d_in, const int* in_sizes, int n_in,
                              void* d_out, int out_size, void* d_ws, size_t ws_size,
                              hipStream_t stream) {
    const float* x  = (const float*)d_in[0];   // [8192, 1024]
    const float* w1 = (const float*)d_in[1];   // [8192, 64]
    const float* w2 = (const float*)d_in[2];   // [8192, 64]
    const float* F  = (const float*)d_in[3];   // [64, 1024, 128]
    const float* Rk = (const float*)d_in[4];   // [64, 128, 1024] = (8192, 1024)
    float* out = (float*)d_out;                // [8192, 1024]

    char* ws = (char*)d_ws;
    const size_t MB = (size_t)1 << 20;

    if (ws_size >= 160 * MB) {
        // ---- main path: pure-GEMM pipeline, 160 MiB footprint ----
        ushort_t* y    = (ushort_t*)ws;               // [0,128) MiB: y, then g in place
        ushort_t* x_bf = (ushort_t*)(ws + 128 * MB);  // [128,144)
        ushort_t* F_t2 = (ushort_t*)(ws + 144 * MB);  // [144,160): F_t2[n*128+r, d]
        ushort_t* Rk_t = x_bf;                        // overlays x_bf after GEMM1

        convert_bf<<<4096, 256, 0, stream>>>(x, x_bf, 1048576);
        // per-n transpose: F[n] (1024x128) -> F_t2[n*128 .. n*128+128) x 1024
        transpose_bf<<<dim3(16, 2, 64), 256, 0, stream>>>(
            F, F_t2, 1024, 128, 131072, 131072);

        // GEMM1: y = x_bf @ F_t2^T   (M=8192, N=8192, K=1024), bf16 out
        kc_gemm<true, 128, 3><<<dim3(64, 64), 256, 0, stream>>>(
            x_bf, F_t2, y, 1024, 1024, 8192, 16);

        // mid: h = w1-reduce(y); y <- g = w2 (x) h   (in place, 16B/lane)
        mid_fuse_v<<<2048, 256, 0, stream>>>(y, w1, w2);

        // Rk_t[d, n*128+r] (1024 x 8192), overlays x_bf (dead)
        transpose_bf<<<dim3(128, 16, 1), 256, 0, stream>>>(
            Rk, Rk_t, 8192, 1024, 0, 0);

        // GEMM2: out = g @ Rk_t^T (M=8192, N=1024, K=8192), fp32 out.
        // 128x64 tiles -> grid 1024 = 4 blocks/CU (was 512 = 2/CU).
        kc_gemm<false, 64, 4><<<dim3(64, 16), 256, 0, stream>>>(
            y, Rk_t, out, 8192, 8192, 1024, 128);
    } else {
        // ---- fallback: round-3 fold pipeline, 38 MiB footprint ----
        float*    h    = (float*)ws;
        ushort_t* x_bf = (ushort_t*)(ws + 4  * MB);
        ushort_t* Rk_t = (ushort_t*)(ws + 4  * MB);   // overlays x_bf after stage 1
        ushort_t* F_t  = (ushort_t*)(ws + 20 * MB);   // F_t[128, 65536]
        ushort_t* h_bf = (ushort_t*)(ws + 36 * MB);

        hipMemsetAsync(h, 0, 4 * MB, stream);
        convert_bf<<<4096, 256, 0, stream>>>(x, x_bf, 1048576);
        transpose_bf<<<dim3(1024, 2, 1), 256, 0, stream>>>(F, F_t, 65536, 128, 0, 0);

        kc_gemm_fold<10, 16, true><<<dim3(128, 1, 8), 256, 0, stream>>>(
            x_bf, w1, F_t, h, 1024, 65536, 128, 128);

        convert_bf<<<512, 256, 0, stream>>>(h, h_bf, 131072);
        transpose_bf<<<dim3(128, 16, 1), 256, 0, stream>>>(Rk, Rk_t, 8192, 1024, 0, 0);

        kc_gemm_fold<7, 2, false><<<dim3(128, 8, 1), 256, 0, stream>>>(
            h_bf, w2, Rk_t, out, 128, 8192, 1024, 128);
    }
}

// Round 8
// 458.542 us; speedup vs baseline: 1.0473x; 1.0473x over previous
//
#include <hip/hip_runtime.h>
#include <stdint.h>

// ---------------------------------------------------------------------------
// KnowledgeCircuit: B=4 S=2048 D=1024 N=64 R=128, M = B*S = 8192 tokens.
// Round 13: GEMM2 split-K=2. Round-12 lesson: TN=64 raised occupancy
// (21->35%) but FETCH doubled (143->304 MB, A re-read by 16 col-blocks) and
// staging/MFMA ratio rose 1.5x -> MfmaUtil DROPPED (42->38), dur 143->166.
// Split-K keeps the known-good TN=128 kernel byte-identical per K-step
// (same staging ratio, same A re-read count) while doubling blocks/CU:
// grid (64,8,2) = 1024 blocks = 4/CU. kz=0 -> fp32 out; kz=1 -> bf16
// partial in the dead F_t2 slot (16 MiB, free after GEMM1). reduce_add
// sums them (80 MiB ~ 14 us).
//   GEMM1: y[m, n*128+r] = sum_d x[m,d] F[n,d,r]   (kc_gemm 128^2, bf16)
//   mid  : h = w1-reduce(y); y <- g = w2 (x) h      (16B/lane, in place)
//   GEMM2: out = g @ Rk_t^T, split-K=2 + reduce     (kc_gemm 128^2, fp32)
// Core GEMM: 2x2 waves, BK=64, global_load_lds, XOR-swizzled LDS (0 confl).
// ---------------------------------------------------------------------------

typedef unsigned short ushort_t;
typedef __attribute__((ext_vector_type(8))) short frag_t;   // 8 bf16
typedef __attribute__((ext_vector_type(4))) float f32x4;

#define BK 64

__device__ __forceinline__ unsigned short f2bf(float f) {
    unsigned int u = __builtin_bit_cast(unsigned int, f);
    u = (u + 0x7FFFu + ((u >> 16) & 1u)) >> 16;   // RTNE
    return (unsigned short)u;
}
__device__ __forceinline__ float bf2f_lo(unsigned int v) {
    return __builtin_bit_cast(float, v << 16);
}
__device__ __forceinline__ float bf2f_hi(unsigned int v) {
    return __builtin_bit_cast(float, v & 0xFFFF0000u);
}

__device__ __forceinline__ void glds16(const ushort_t* g, ushort_t* l) {
    __builtin_amdgcn_global_load_lds(
        (const __attribute__((address_space(1))) unsigned int*)g,
        (__attribute__((address_space(3))) unsigned int*)l,
        16, 0, 0);
}

// ---------------- prepass: fp32 -> bf16 elementwise -------------------------
__global__ __launch_bounds__(256) void convert_bf(const float* __restrict__ in,
                                                  ushort_t* __restrict__ out, int n8) {
    int idx = blockIdx.x * 256 + threadIdx.x;
    if (idx >= n8) return;
    const float4 v0 = ((const float4*)in)[idx * 2];
    const float4 v1 = ((const float4*)in)[idx * 2 + 1];
    unsigned short b[8] = { f2bf(v0.x), f2bf(v0.y), f2bf(v0.z), f2bf(v0.w),
                            f2bf(v1.x), f2bf(v1.y), f2bf(v1.z), f2bf(v1.w) };
    ((uint4*)out)[idx] = *(const uint4*)b;
}

// ---------------- prepass: fp32 RxC -> bf16 CxR transpose (batched) ---------
__global__ __launch_bounds__(256) void transpose_bf(const float* __restrict__ in,
                                                    ushort_t* __restrict__ out,
                                                    int R, int C,
                                                    long in_bstride, long out_bstride) {
    __shared__ float tile[64][65];
    in  += (long)blockIdx.z * in_bstride;
    out += (long)blockIdx.z * out_bstride;
    const int t  = threadIdx.x;
    const int r0 = blockIdx.x * 64;
    const int c0 = blockIdx.y * 64;
    const int ci = t & 63;
    const int rb = t >> 6;
    #pragma unroll
    for (int p = 0; p < 16; ++p)
        tile[rb + 4 * p][ci] = in[(size_t)(r0 + rb + 4 * p) * C + c0 + ci];
    __syncthreads();
    const int cw = t >> 2;
    const int rg = (t & 3) * 16;
    unsigned short buf[16];
    #pragma unroll
    for (int k = 0; k < 16; ++k)
        buf[k] = f2bf(tile[rg + k][cw]);
    uint4* dst = (uint4*)&out[(size_t)(c0 + cw) * R + r0 + rg];
    dst[0] = *(const uint4*)&buf[0];
    dst[1] = *(const uint4*)&buf[8];
}

// ---------------- mid (vectorized): h = w1-reduce(y); y <- g = w2 (x) h -----
// One wave per token row. Lane l: n-class ng = l>>4 (n = 4i+ng, i=0..15),
// rp-quad rp4 = l&15. 16B/lane fully coalesced both directions;
// h partials combined across the 4 n-classes via shfl_xor 16/32.
__global__ __launch_bounds__(256) void mid_fuse_v(ushort_t* __restrict__ y,
                                                  const float* __restrict__ w1,
                                                  const float* __restrict__ w2) {
    const int m    = blockIdx.x * 4 + (threadIdx.x >> 6);
    const int lane = threadIdx.x & 63;
    uint4* yrow = (uint4*)(y + (size_t)m * 8192);   // 1024 uint4 per row
    const float* w1r = w1 + (size_t)m * 64;
    const float* w2r = w2 + (size_t)m * 64;
    const int ng  = lane >> 4;
    const int rp4 = lane & 15;

    float h[8];
    #pragma unroll
    for (int k = 0; k < 8; ++k) h[k] = 0.f;

    #pragma unroll
    for (int i = 0; i < 16; ++i) {
        const int n = i * 4 + ng;
        const uint4 v = yrow[n * 16 + rp4];        // u32 idx n*64 + rp4*4
        const float w = w1r[n];
        h[0] += w * bf2f_lo(v.x); h[1] += w * bf2f_hi(v.x);
        h[2] += w * bf2f_lo(v.y); h[3] += w * bf2f_hi(v.y);
        h[4] += w * bf2f_lo(v.z); h[5] += w * bf2f_hi(v.z);
        h[6] += w * bf2f_lo(v.w); h[7] += w * bf2f_hi(v.w);
    }
    #pragma unroll
    for (int k = 0; k < 8; ++k) {
        h[k] += __shfl_xor(h[k], 16, 64);
        h[k] += __shfl_xor(h[k], 32, 64);
    }
    // g[m, n*128+r] = w2[m,n] * h[m,r], written in place (same coords as read)
    #pragma unroll
    for (int i = 0; i < 16; ++i) {
        const int n = i * 4 + ng;
        const float w = w2r[n];
        uint4 o;
        o.x = (unsigned)f2bf(w * h[0]) | ((unsigned)f2bf(w * h[1]) << 16);
        o.y = (unsigned)f2bf(w * h[2]) | ((unsigned)f2bf(w * h[3]) << 16);
        o.z = (unsigned)f2bf(w * h[4]) | ((unsigned)f2bf(w * h[5]) << 16);
        o.w = (unsigned)f2bf(w * h[6]) | ((unsigned)f2bf(w * h[7]) << 16);
        yrow[n * 16 + rp4] = o;
    }
}

// ---------------- reduce: out += bf16(partial) ------------------------------
__global__ __launch_bounds__(256) void reduce_add(float* __restrict__ out,
                                                  const ushort_t* __restrict__ part,
                                                  int n8) {
    int idx = blockIdx.x * 256 + threadIdx.x;
    if (idx >= n8) return;
    const uint4 p = ((const uint4*)part)[idx];
    float4 a = ((const float4*)out)[idx * 2];
    float4 b = ((const float4*)out)[idx * 2 + 1];
    a.x += bf2f_lo(p.x); a.y += bf2f_hi(p.x);
    a.z += bf2f_lo(p.y); a.w += bf2f_hi(p.y);
    b.x += bf2f_lo(p.z); b.y += bf2f_hi(p.z);
    b.z += bf2f_lo(p.w); b.w += bf2f_hi(p.w);
    ((float4*)out)[idx * 2]     = a;
    ((float4*)out)[idx * 2 + 1] = b;
}

// ---------------- pure GEMM (128x128, split-K capable) ----------------------
// C[m,n] = sum_k Ab[m,k] * Bt[n,k] over this block's K-slice.
// gridDim.z slices K: slice kz covers ksteps steps starting at kz*ksteps*BK.
// kz==0 (or OUT_BF16) writes Cout; kz>0 writes bf16 into Cpart.
// 128x128 block, 2x2 waves, 64x64/wave — K-step schedule byte-identical to
// the round-5 known-good kernel.
template<bool OUT_BF16>
__global__ __launch_bounds__(256, 3)
void kc_gemm(const ushort_t* __restrict__ Ab, const ushort_t* __restrict__ Bt,
             void* __restrict__ Cout, ushort_t* __restrict__ Cpart,
             int ldA, int ldB, int ldC, int ksteps)
{
    __shared__ ushort_t As[128 * BK];   // 16 KB: 8 chunks(16B)/row, XOR-swizzled
    __shared__ ushort_t Bs[128 * BK];   // 16 KB

    const int t    = threadIdx.x;
    const int lane = t & 63;
    const int wv   = t >> 6;
    const int m0   = blockIdx.x * 128;
    const int n0   = blockIdx.y * 128;
    const int koff = blockIdx.z * ksteps * BK;

    const int wm = (wv & 1) * 64;
    const int wn = (wv >> 1) * 64;
    const int fr = lane & 15;
    const int q  = lane >> 4;
    const int e  = fr & 7;

    int srow[4], scol[4];
    #pragma unroll
    for (int c = 0; c < 4; ++c) {
        const int s = (wv * 4 + c) * 64 + lane;
        srow[c] = s >> 3;
        scol[c] = ((s & 7) ^ (srow[c] & 7)) * 8;   // XOR swizzle in global k
    }

    f32x4 acc[4][4];
    #pragma unroll
    for (int i = 0; i < 4; ++i)
        #pragma unroll
        for (int j = 0; j < 4; ++j)
            acc[i][j] = (f32x4){0.f, 0.f, 0.f, 0.f};

    for (int ss = 0; ss < ksteps; ++ss) {
        const int k0 = koff + ss * BK;

        __syncthreads();
        #pragma unroll
        for (int c = 0; c < 4; ++c)
            glds16(Ab + (size_t)(m0 + srow[c]) * ldA + k0 + scol[c],
                   &As[(wv * 4 + c) * 512]);
        #pragma unroll
        for (int c = 0; c < 4; ++c)
            glds16(Bt + (size_t)(n0 + srow[c]) * ldB + k0 + scol[c],
                   &Bs[(wv * 4 + c) * 512]);
        __syncthreads();

        #pragma unroll
        for (int kk = 0; kk < 2; ++kk) {
            const int csw = (kk * 4 + q) ^ e;
            frag_t a[4], b[4];
            #pragma unroll
            for (int i = 0; i < 4; ++i)
                a[i] = *(const frag_t*)&As[((wm + 16 * i + fr) * 8 + csw) * 8];
            #pragma unroll
            for (int j = 0; j < 4; ++j)
                b[j] = *(const frag_t*)&Bs[((wn + 16 * j + fr) * 8 + csw) * 8];
            #pragma unroll
            for (int i = 0; i < 4; ++i)
                #pragma unroll
                for (int j = 0; j < 4; ++j)
                    acc[i][j] = __builtin_amdgcn_mfma_f32_16x16x32_bf16(
                                    a[i], b[j], acc[i][j], 0, 0, 0);
        }
    }

    // epilogue: C/D layout col=lane&15, row=q*4+reg
    const bool main_out = OUT_BF16 || (blockIdx.z == 0);
    #pragma unroll
    for (int i = 0; i < 4; ++i) {
        #pragma unroll
        for (int r = 0; r < 4; ++r) {
            const int gm = m0 + wm + 16 * i + q * 4 + r;
            #pragma unroll
            for (int j = 0; j < 4; ++j) {
                const int gn = n0 + wn + 16 * j + fr;
                if (main_out) {
                    if constexpr (OUT_BF16)
                        ((ushort_t*)Cout)[(size_t)gm * ldC + gn] = f2bf(acc[i][j][r]);
                    else
                        ((float*)Cout)[(size_t)gm * ldC + gn] = acc[i][j][r];
                } else {
                    Cpart[(size_t)gm * ldC + gn] = f2bf(acc[i][j][r]);
                }
            }
        }
    }
}

// ---------------- fallback fold-GEMM (round-3, known-good) ------------------
template<int SHIFT, int SEG_STEPS, bool ATOMIC>
__global__ __launch_bounds__(256, 4)
void kc_gemm_fold(const ushort_t* __restrict__ Ab, const float* __restrict__ W,
                  const ushort_t* __restrict__ Bt, float* __restrict__ C,
                  int ldA, int ldB, int ldC, int ksteps)
{
    __shared__ ushort_t As[64 * BK];
    __shared__ ushort_t Bs[128 * BK];
    const int t = threadIdx.x, lane = t & 63, wv = t >> 6;
    const int m0 = blockIdx.x * 64, n0 = blockIdx.y * 128;
    const int kbase = blockIdx.z * ksteps * BK;
    const int wm = (wv & 1) * 32, wn = (wv >> 1) * 64;
    const int fr = lane & 15, q = lane >> 4, e = fr & 7;
    int arow[2], acol[2], brow[4], bcol[4];
    #pragma unroll
    for (int c = 0; c < 2; ++c) {
        const int s = (wv * 2 + c) * 64 + lane;
        arow[c] = s >> 3; acol[c] = ((s & 7) ^ (arow[c] & 7)) * 8;
    }
    #pragma unroll
    for (int c = 0; c < 4; ++c) {
        const int s = (wv * 4 + c) * 64 + lane;
        brow[c] = s >> 3; bcol[c] = ((s & 7) ^ (brow[c] & 7)) * 8;
    }
    f32x4 acc_out[2][4];
    #pragma unroll
    for (int i = 0; i < 2; ++i)
        #pragma unroll
        for (int j = 0; j < 4; ++j) acc_out[i][j] = (f32x4){0.f,0.f,0.f,0.f};
    const int nsegs = ksteps / SEG_STEPS;
    for (int seg = 0; seg < nsegs; ++seg) {
        const int segk = kbase + seg * SEG_STEPS * BK;
        const int nidx = segk >> SHIFT;
        f32x4 acc_in[2][4];
        #pragma unroll
        for (int i = 0; i < 2; ++i)
            #pragma unroll
            for (int j = 0; j < 4; ++j) acc_in[i][j] = (f32x4){0.f,0.f,0.f,0.f};
        for (int ss = 0; ss < SEG_STEPS; ++ss) {
            const int k0 = segk + ss * BK;
            const int d0 = k0 & ((1 << SHIFT) - 1);
            __syncthreads();
            #pragma unroll
            for (int c = 0; c < 2; ++c)
                glds16(Ab + (size_t)(m0 + arow[c]) * ldA + d0 + acol[c],
                       &As[(wv * 2 + c) * 512]);
            #pragma unroll
            for (int c = 0; c < 4; ++c)
                glds16(Bt + (size_t)(n0 + brow[c]) * ldB + k0 + bcol[c],
                       &Bs[(wv * 4 + c) * 512]);
            __syncthreads();
            #pragma unroll
            for (int kk = 0; kk < 2; ++kk) {
                const int csw = (kk * 4 + q) ^ e;
                frag_t a[2], b[4];
                #pragma unroll
                for (int i = 0; i < 2; ++i)
                    a[i] = *(const frag_t*)&As[((wm + 16*i + fr) * 8 + csw) * 8];
                #pragma unroll
                for (int j = 0; j < 4; ++j)
                    b[j] = *(const frag_t*)&Bs[((wn + 16*j + fr) * 8 + csw) * 8];
                #pragma unroll
                for (int i = 0; i < 2; ++i)
                    #pragma unroll
                    for (int j = 0; j < 4; ++j)
                        acc_in[i][j] = __builtin_amdgcn_mfma_f32_16x16x32_bf16(
                                           a[i], b[j], acc_in[i][j], 0, 0, 0);
            }
        }
        #pragma unroll
        for (int i = 0; i < 2; ++i)
            #pragma unroll
            for (int r = 0; r < 4; ++r) {
                const int gm = m0 + wm + 16*i + q*4 + r;
                const float w = W[(size_t)gm * 64 + nidx];
                #pragma unroll
                for (int j = 0; j < 4; ++j) acc_out[i][j][r] += w * acc_in[i][j][r];
            }
    }
    #pragma unroll
    for (int i = 0; i < 2; ++i)
        #pragma unroll
        for (int j = 0; j < 4; ++j)
            #pragma unroll
            for (int r = 0; r < 4; ++r) {
                const int gm = m0 + wm + 16*i + q*4 + r;
                const int gn = n0 + wn + 16*j + fr;
                if constexpr (ATOMIC) atomicAdd(&C[(size_t)gm * ldC + gn], acc_out[i][j][r]);
                else C[(size_t)gm * ldC + gn] = acc_out[i][j][r];
            }
}

extern "C" void kernel_launch(void* const* d_in, const int* in_sizes, int n_in,
                              void* d_out, int out_size, void* d_ws, size_t ws_size,
                              hipStream_t stream) {
    const float* x  = (const float*)d_in[0];   // [8192, 1024]
    const float* w1 = (const float*)d_in[1];   // [8192, 64]
    const float* w2 = (const float*)d_in[2];   // [8192, 64]
    const float* F  = (const float*)d_in[3];   // [64, 1024, 128]
    const float* Rk = (const float*)d_in[4];   // [64, 128, 1024] = (8192, 1024)
    float* out = (float*)d_out;                // [8192, 1024]

    char* ws = (char*)d_ws;
    const size_t MB = (size_t)1 << 20;

    if (ws_size >= 160 * MB) {
        // ---- main path: pure-GEMM pipeline, 160 MiB footprint ----
        ushort_t* y    = (ushort_t*)ws;               // [0,128) MiB: y, then g in place
        ushort_t* x_bf = (ushort_t*)(ws + 128 * MB);  // [128,144)
        ushort_t* F_t2 = (ushort_t*)(ws + 144 * MB);  // [144,160): F_t2[n*128+r, d]
        ushort_t* Rk_t = x_bf;                        // overlays x_bf after GEMM1
        ushort_t* part = F_t2;                        // overlays F_t2 after GEMM1
                                                      // (bf16 [8192,1024] = 16 MiB)

        convert_bf<<<4096, 256, 0, stream>>>(x, x_bf, 1048576);
        // per-n transpose: F[n] (1024x128) -> F_t2[n*128 .. n*128+128) x 1024
        transpose_bf<<<dim3(16, 2, 64), 256, 0, stream>>>(
            F, F_t2, 1024, 128, 131072, 131072);

        // GEMM1: y = x_bf @ F_t2^T   (M=8192, N=8192, K=1024), bf16 out
        kc_gemm<true><<<dim3(64, 64), 256, 0, stream>>>(
            x_bf, F_t2, y, nullptr, 1024, 1024, 8192, 16);

        // mid: h = w1-reduce(y); y <- g = w2 (x) h   (in place, 16B/lane)
        mid_fuse_v<<<2048, 256, 0, stream>>>(y, w1, w2);

        // Rk_t[d, n*128+r] (1024 x 8192), overlays x_bf (dead)
        transpose_bf<<<dim3(128, 16, 1), 256, 0, stream>>>(
            Rk, Rk_t, 8192, 1024, 0, 0);

        // GEMM2: out = g @ Rk_t^T (M=8192, N=1024, K=8192), split-K=2.
        // grid (64,8,2) = 1024 blocks = 4/CU; kz=0 -> fp32 out,
        // kz=1 -> bf16 partial in dead F_t2 slot. Then reduce.
        kc_gemm<false><<<dim3(64, 8, 2), 256, 0, stream>>>(
            y, Rk_t, out, part, 8192, 8192, 1024, 64);
        reduce_add<<<4096, 256, 0, stream>>>(out, part, 1048576);
    } else {
        // ---- fallback: round-3 fold pipeline, 38 MiB footprint ----
        float*    h    = (float*)ws;
        ushort_t* x_bf = (ushort_t*)(ws + 4  * MB);
        ushort_t* Rk_t = (ushort_t*)(ws + 4  * MB);   // overlays x_bf after stage 1
        ushort_t* F_t  = (ushort_t*)(ws + 20 * MB);   // F_t[128, 65536]
        ushort_t* h_bf = (ushort_t*)(ws + 36 * MB);

        hipMemsetAsync(h, 0, 4 * MB, stream);
        convert_bf<<<4096, 256, 0, stream>>>(x, x_bf, 1048576);
        transpose_bf<<<dim3(1024, 2, 1), 256, 0, stream>>>(F, F_t, 65536, 128, 0, 0);

        kc_gemm_fold<10, 16, true><<<dim3(128, 1, 8), 256, 0, stream>>>(
            x_bf, w1, F_t, h, 1024, 65536, 128, 128);

        convert_bf<<<512, 256, 0, stream>>>(h, h_bf, 131072);
        transpose_bf<<<dim3(128, 16, 1), 256, 0, stream>>>(Rk, Rk_t, 8192, 1024, 0, 0);

        kc_gemm_fold<7, 2, false><<<dim3(128, 8, 1), 256, 0, stream>>>(
            h_bf, w2, Rk_t, out, 128, 8192, 1024, 128);
    }
}